// Round 2
// baseline (5325.529 us; speedup 1.0000x reference)
//
#include <hip/hip_runtime.h>
#include <cstdint>
#include <cstddef>

// ---------------- types ----------------
typedef __attribute__((ext_vector_type(8))) short short8;   // 8 bf16 in 4 VGPRs
typedef __attribute__((ext_vector_type(4))) float f32x4;
typedef __attribute__((ext_vector_type(2))) unsigned int u32x2;

// ---------------- problem dims ----------------
// T=64 B=256 E=1536 A=6 H=2048 L=1024 AL=128; P_IN=2176 Q_IN=3712
static constexpr size_t NHOUT = 33554432ULL;  // T*B*H
static constexpr size_t NLOUT = 16777216ULL;  // T*B*L

__device__ __forceinline__ unsigned short f2bf(float f) {
  union { float f; unsigned u; } v; v.f = f;
  unsigned r = v.u + 0x7fffu + ((v.u >> 16) & 1u);
  return (unsigned short)(r >> 16);
}

__device__ __forceinline__ void gload16(const void* g, void* l) {
  __builtin_amdgcn_global_load_lds(
      (__attribute__((address_space(1))) void*)(void*)g,
      (__attribute__((address_space(3))) void*)l, 16, 0, 0);
}

// ---------------- weight transpose + fp32->bf16 ----------------
// W [K,N] row-major fp32  ->  Wt [N,K] row-major bf16
__global__ void transpose_cvt(const float* __restrict__ W, short* __restrict__ Wt,
                              int K, int N) {
  __shared__ short t[32][33];
  int n0 = blockIdx.x * 32, k0 = blockIdx.y * 32;
  int x = threadIdx.x, y = threadIdx.y;   // block (32,8)
#pragma unroll
  for (int i = 0; i < 4; ++i) {
    int k = k0 + y + i * 8;
    t[y + i * 8][x] = (short)f2bf(W[(size_t)k * N + n0 + x]);
  }
  __syncthreads();
#pragma unroll
  for (int i = 0; i < 4; ++i) {
    int n = n0 + y + i * 8;
    Wt[(size_t)n * K + k0 + x] = t[x][y + i * 8];
  }
}

// ---------------- generic bf16 GEMM: C = A[M,K] * Bt[N,K]^T + bias ----------------
// tiles: BM=BN=128, BK=64. 256 threads = 4 waves (2x2), 4x4 16x16x32 frags per wave.
// LDS layout: As/Bs [128 rows][64 bf16], XOR-swizzled: byte ^= ((row&7)<<4).
// Staged via global_load_lds width16 with pre-swizzled global source (rule #21).
// mode 0: fp32 out (ldc)   mode 1: bf16 out (ldc)
// mode 2: head: col<1024 -> mu (fp32, ld 1024); col>=1024 -> sigma (fp32, ld 1024)
__global__ __launch_bounds__(256, 2) void gemm_bt(
    const short* __restrict__ A, int lda,
    const short* __restrict__ Bt, int ldb,
    const float* __restrict__ bias,
    void* __restrict__ out0, float* __restrict__ out2,
    int K, int ldc, int mode) {
  __shared__ __align__(16) char lds[32768];
  char* As = lds;
  char* Bs = lds + 16384;
  const int tid = threadIdx.x;
  const int lane = tid & 63;
  const int w = tid >> 6;
  const int bn0 = blockIdx.x * 128;
  const int bm0 = blockIdx.y * 128;

  // staging geometry: 16KB per tile = 16 segs of 1KB; wave w handles segs w*4..w*4+3
  int segS[4];
  size_t aoff[4], boff[4];
#pragma unroll
  for (int i = 0; i < 4; ++i) {
    int seg = w * 4096 + i * 1024;
    int o = seg + lane * 16;                    // linear LDS byte this lane fills
    int p = o ^ (((o >> 7) & 7) << 4);          // logical byte (inverse swizzle)
    int row = p >> 7, kb = p & 127;             // tile row, k-byte
    segS[i] = seg;
    aoff[i] = ((size_t)(bm0 + row) * lda) * 2 + kb;
    boff[i] = ((size_t)(bn0 + row) * ldb) * 2 + kb;
  }
  const char* Ac = (const char*)A;
  const char* Bc = (const char*)Bt;

  f32x4 acc[4][4];
#pragma unroll
  for (int i = 0; i < 4; ++i)
#pragma unroll
    for (int j = 0; j < 4; ++j) acc[i][j] = (f32x4){0.f, 0.f, 0.f, 0.f};

  const int wm = (w >> 1) * 64;
  const int wn = (w & 1) * 64;
  int arow[4], brow[4];
#pragma unroll
  for (int i = 0; i < 4; ++i) {
    arow[i] = wm + i * 16 + (lane & 15);
    brow[i] = wn + i * 16 + (lane & 15);
  }
  const int kpart = (lane >> 4) * 16;

  for (int k0 = 0; k0 < K; k0 += 64) {
#pragma unroll
    for (int i = 0; i < 4; ++i) {
      gload16(Ac + aoff[i] + (size_t)k0 * 2, As + segS[i]);
      gload16(Bc + boff[i] + (size_t)k0 * 2, Bs + segS[i]);
    }
    __syncthreads();
#pragma unroll
    for (int kk = 0; kk < 2; ++kk) {
      short8 af[4], bfr[4];
#pragma unroll
      for (int i = 0; i < 4; ++i) {
        int byt = (arow[i] * 128 + kk * 64 + kpart) ^ ((arow[i] & 7) << 4);
        af[i] = *(const short8*)(As + byt);
      }
#pragma unroll
      for (int i = 0; i < 4; ++i) {
        int byt = (brow[i] * 128 + kk * 64 + kpart) ^ ((brow[i] & 7) << 4);
        bfr[i] = *(const short8*)(Bs + byt);
      }
#pragma unroll
      for (int mi = 0; mi < 4; ++mi)
#pragma unroll
        for (int ni = 0; ni < 4; ++ni)
          acc[mi][ni] = __builtin_amdgcn_mfma_f32_16x16x32_bf16(
              af[mi], bfr[ni], acc[mi][ni], 0, 0, 0);
    }
    __syncthreads();
  }

  // epilogue. C/D layout: col = lane&15, row = (lane>>4)*4 + j  [m89-verified]
#pragma unroll
  for (int ni = 0; ni < 4; ++ni) {
    int col = bn0 + wn + ni * 16 + (lane & 15);
    float bv = bias ? bias[col] : 0.0f;
#pragma unroll
    for (int mi = 0; mi < 4; ++mi) {
      int row = bm0 + wm + mi * 16 + ((lane >> 4) << 2);
      f32x4 v = acc[mi][ni];
#pragma unroll
      for (int j = 0; j < 4; ++j) {
        float val = v[j] + bv;
        size_t r = (size_t)(row + j);
        if (mode == 0) {
          ((float*)out0)[r * ldc + col] = val;
        } else if (mode == 1) {
          ((short*)out0)[r * ldc + col] = (short)f2bf(val);
        } else {
          if (col < 1024)
            ((float*)out0)[r * 1024 + col] = val;
          else
            out2[r * 1024 + (col - 1024)] =
                0.9f / (1.0f + __expf(-val * (1.0f / 0.9f))) + 0.1f;
        }
      }
    }
  }
}

// ---------------- h0/z0 prep ----------------
__global__ void prep_k(const float* __restrict__ h0, const float* __restrict__ z0,
                       float* __restrict__ h, short* __restrict__ hbf,
                       short* __restrict__ zbf) {
  int i = (blockIdx.x * 256 + threadIdx.x) * 4;
  if (i < 524288) {
    f32x4 v = *(const f32x4*)(h0 + i);
    *(f32x4*)(h + i) = v;
    unsigned u0 = f2bf(v[0]) | ((unsigned)f2bf(v[1]) << 16);
    unsigned u1 = f2bf(v[2]) | ((unsigned)f2bf(v[3]) << 16);
    *(u32x2*)(hbf + i) = (u32x2){u0, u1};
  }
  if (i < 262144) {
    f32x4 v = *(const f32x4*)(z0 + i);
    unsigned u0 = f2bf(v[0]) | ((unsigned)f2bf(v[1]) << 16);
    unsigned u1 = f2bf(v[2]) | ((unsigned)f2bf(v[3]) << 16);
    *(u32x2*)(zbf + i) = (u32x2){u0, u1};
  }
}

// ---------------- action projections -> Xp/Xq tails ----------------
__global__ void act_k(const float* __restrict__ act, const float* __restrict__ Wp,
                      const float* __restrict__ bp, const float* __restrict__ Wq,
                      const float* __restrict__ bq, short* __restrict__ xp,
                      short* __restrict__ xq) {
  int idx = blockIdx.x * 256 + threadIdx.x;  // T*B*128 = 2,097,152
  int l = idx & 127;
  int rb = idx >> 7;
  float a0 = act[(size_t)rb * 6 + 0], a1 = act[(size_t)rb * 6 + 1];
  float a2 = act[(size_t)rb * 6 + 2], a3 = act[(size_t)rb * 6 + 3];
  float a4 = act[(size_t)rb * 6 + 4], a5 = act[(size_t)rb * 6 + 5];
  float sp = bp[l] + a0 * Wp[l] + a1 * Wp[128 + l] + a2 * Wp[256 + l] +
             a3 * Wp[384 + l] + a4 * Wp[512 + l] + a5 * Wp[640 + l];
  float sq = bq[l] + a0 * Wq[l] + a1 * Wq[128 + l] + a2 * Wq[256 + l] +
             a3 * Wq[384 + l] + a4 * Wq[512 + l] + a5 * Wq[640 + l];
  xp[(size_t)rb * 2176 + 2048 + l] = (short)f2bf(sp);
  xq[(size_t)rb * 3712 + 3584 + l] = (short)f2bf(sq);
}

// ---------------- embeds -> Xq middle ----------------
__global__ void emb_k(const float* __restrict__ e, short* __restrict__ xq) {
  int i = (blockIdx.x * 256 + threadIdx.x) * 4;  // over 25,165,824
  int rb = i / 1536;
  int c = i - rb * 1536;
  f32x4 v = *(const f32x4*)(e + i);
  unsigned u0 = f2bf(v[0]) | ((unsigned)f2bf(v[1]) << 16);
  unsigned u1 = f2bf(v[2]) | ((unsigned)f2bf(v[3]) << 16);
  *(u32x2*)(xq + (size_t)rb * 3712 + 2048 + c) = (u32x2){u0, u1};
}

// ---------------- GRU elementwise ----------------
__global__ void gru_ew(const float* __restrict__ gx, const float* __restrict__ gh,
                       float* __restrict__ h, short* __restrict__ hbf,
                       float* __restrict__ outh, short* __restrict__ xp,
                       short* __restrict__ xq) {
  int i = (blockIdx.x * 256 + threadIdx.x) * 4;  // over 524288
  int b = i >> 11;
  int j = i & 2047;
  size_t g = (size_t)b * 6144 + j;
  f32x4 xr = *(const f32x4*)(gx + g);
  f32x4 xz = *(const f32x4*)(gx + g + 2048);
  f32x4 xn = *(const f32x4*)(gx + g + 4096);
  f32x4 hr = *(const f32x4*)(gh + g);
  f32x4 hz = *(const f32x4*)(gh + g + 2048);
  f32x4 hn = *(const f32x4*)(gh + g + 4096);
  f32x4 hp = *(const f32x4*)(h + i);
  f32x4 hv;
#pragma unroll
  for (int e = 0; e < 4; ++e) {
    float r = 1.f / (1.f + __expf(-(xr[e] + hr[e])));
    float z = 1.f / (1.f + __expf(-(xz[e] + hz[e])));
    float n = tanhf(xn[e] + r * hn[e]);
    hv[e] = (1.f - z) * n + z * hp[e];
  }
  *(f32x4*)(h + i) = hv;
  *(f32x4*)(outh + i) = hv;
  unsigned u0 = f2bf(hv[0]) | ((unsigned)f2bf(hv[1]) << 16);
  unsigned u1 = f2bf(hv[2]) | ((unsigned)f2bf(hv[3]) << 16);
  u32x2 uu = (u32x2){u0, u1};
  *(u32x2*)(hbf + i) = uu;
  *(u32x2*)(xp + (size_t)b * 2176 + j) = uu;
  *(u32x2*)(xq + (size_t)b * 3712 + j) = uu;
}

// ---------------- sampling: samp = mu + noise * sigma ----------------
__global__ void samp_k(const float* __restrict__ npz, const float* __restrict__ nqz,
                       float* __restrict__ out) {
  size_t i = ((size_t)blockIdx.x * 256 + threadIdx.x) * 4;  // over 16,777,216
  float* pmu = out + NHOUT;
  float* psig = pmu + NLOUT;
  float* psam = psig + NLOUT;
  float* qmu = psam + NLOUT;
  float* qsig = qmu + NLOUT;
  float* qsam = qsig + NLOUT;
  f32x4 mu = *(const f32x4*)(pmu + i);
  f32x4 sg = *(const f32x4*)(psig + i);
  f32x4 nz = *(const f32x4*)(npz + i);
  *(f32x4*)(psam + i) = mu + nz * sg;
  mu = *(const f32x4*)(qmu + i);
  sg = *(const f32x4*)(qsig + i);
  nz = *(const f32x4*)(nqz + i);
  *(f32x4*)(qsam + i) = mu + nz * sg;
}

// ---------------- launcher ----------------
extern "C" void kernel_launch(void* const* d_in, const int* in_sizes, int n_in,
                              void* d_out, int out_size, void* d_ws, size_t ws_size,
                              hipStream_t stream) {
  (void)in_sizes; (void)n_in; (void)out_size; (void)ws_size;
  const float* embeds  = (const float*)d_in[0];
  const float* actions = (const float*)d_in[1];
  const float* h0      = (const float*)d_in[2];
  const float* z0      = (const float*)d_in[3];
  const float* noise_p = (const float*)d_in[4];
  const float* noise_q = (const float*)d_in[5];
  const float* W_pre = (const float*)d_in[6];
  const float* b_pre = (const float*)d_in[7];
  const float* W_ih  = (const float*)d_in[8];
  const float* W_hh  = (const float*)d_in[9];
  const float* b_ih  = (const float*)d_in[10];
  const float* b_hh  = (const float*)d_in[11];
  const float* W_pa  = (const float*)d_in[12];
  const float* b_pa  = (const float*)d_in[13];
  const float* W_qa  = (const float*)d_in[14];
  const float* b_qa  = (const float*)d_in[15];
  const float* pW1 = (const float*)d_in[16];
  const float* pb1 = (const float*)d_in[17];
  const float* pW2 = (const float*)d_in[18];
  const float* pb2 = (const float*)d_in[19];
  const float* qW1 = (const float*)d_in[20];
  const float* qb1 = (const float*)d_in[21];
  const float* qW2 = (const float*)d_in[22];
  const float* qb2 = (const float*)d_in[23];

  char* ws = (char*)d_ws;
  size_t off = 0;
  auto alloc = [&](size_t bytes) -> char* {
    char* p = ws + off;
    off += (bytes + 255) & ~(size_t)255;
    return p;
  };
  short* WpreT = (short*)alloc((size_t)2048 * 1024 * 2);
  short* WihT  = (short*)alloc((size_t)6144 * 2048 * 2);
  short* WhhT  = (short*)alloc((size_t)6144 * 2048 * 2);
  short* pW1T  = (short*)alloc((size_t)2176 * 2176 * 2);
  short* pW2T  = (short*)alloc((size_t)2048 * 2176 * 2);
  short* qW1T  = (short*)alloc((size_t)3712 * 3712 * 2);
  short* qW2T  = (short*)alloc((size_t)2048 * 3712 * 2);
  short* Xp    = (short*)alloc((size_t)16384 * 2176 * 2);
  short* Xq    = (short*)alloc((size_t)16384 * 3712 * 2);
  short* Y1p   = (short*)alloc((size_t)4096 * 2176 * 2);
  short* Y1q   = (short*)alloc((size_t)4096 * 3712 * 2);
  float* gx    = (float*)alloc((size_t)256 * 6144 * 4);
  float* gh    = (float*)alloc((size_t)256 * 6144 * 4);
  float* hbuf  = (float*)alloc((size_t)256 * 2048 * 4);
  short* hbf   = (short*)alloc((size_t)256 * 2048 * 2);
  short* zbf   = (short*)alloc((size_t)256 * 1024 * 2);
  short* intbf = (short*)alloc((size_t)256 * 2048 * 2);

  float* out = (float*)d_out;
  float* p_mu  = out + NHOUT;
  float* p_sig = p_mu + NLOUT;
  float* q_mu  = out + NHOUT + 3 * NLOUT;
  float* q_sig = q_mu + NLOUT;

  dim3 tb(32, 8);
  transpose_cvt<<<dim3(64, 32), tb, 0, stream>>>(W_pre, WpreT, 1024, 2048);
  transpose_cvt<<<dim3(192, 64), tb, 0, stream>>>(W_ih, WihT, 2048, 6144);
  transpose_cvt<<<dim3(192, 64), tb, 0, stream>>>(W_hh, WhhT, 2048, 6144);
  transpose_cvt<<<dim3(68, 68), tb, 0, stream>>>(pW1, pW1T, 2176, 2176);
  transpose_cvt<<<dim3(64, 68), tb, 0, stream>>>(pW2, pW2T, 2176, 2048);
  transpose_cvt<<<dim3(116, 116), tb, 0, stream>>>(qW1, qW1T, 3712, 3712);
  transpose_cvt<<<dim3(64, 116), tb, 0, stream>>>(qW2, qW2T, 3712, 2048);

  prep_k<<<512, 256, 0, stream>>>(h0, z0, hbuf, hbf, zbf);
  act_k<<<8192, 256, 0, stream>>>(actions, W_pa, b_pa, W_qa, b_qa, Xp, Xq);
  emb_k<<<24576, 256, 0, stream>>>(embeds, Xq);

  // in_t = z0 @ W_pre + b_pre  (M=256,N=2048,K=1024) -> bf16
  gemm_bt<<<dim3(16, 2), 256, 0, stream>>>(zbf, 1024, WpreT, 1024, b_pre,
                                           intbf, nullptr, 1024, 2048, 1);
  // gx = in_t @ W_ih + b_ih  (M=256,N=6144,K=2048) -> fp32
  gemm_bt<<<dim3(48, 2), 256, 0, stream>>>(intbf, 2048, WihT, 2048, b_ih,
                                           gx, nullptr, 2048, 6144, 0);

  // sequential GRU chain
  for (int t = 0; t < 64; ++t) {
    gemm_bt<<<dim3(48, 2), 256, 0, stream>>>(hbf, 2048, WhhT, 2048, b_hh,
                                             gh, nullptr, 2048, 6144, 0);
    gru_ew<<<512, 256, 0, stream>>>(gx, gh, hbuf, hbf,
                                    out + (size_t)t * 524288,
                                    Xp + (size_t)t * 256 * 2176,
                                    Xq + (size_t)t * 256 * 3712);
  }

  // batched prior/posterior MLPs, 4 chunks of 16 timesteps (M=4096)
  for (int c = 0; c < 4; ++c) {
    const short* xpc = Xp + (size_t)c * 4096 * 2176;
    const short* xqc = Xq + (size_t)c * 4096 * 3712;
    gemm_bt<<<dim3(17, 32), 256, 0, stream>>>(xpc, 2176, pW1T, 2176, pb1,
                                              Y1p, nullptr, 2176, 2176, 1);
    gemm_bt<<<dim3(16, 32), 256, 0, stream>>>(Y1p, 2176, pW2T, 2176, pb2,
                                              p_mu + (size_t)c * 4194304,
                                              p_sig + (size_t)c * 4194304, 2176, 0, 2);
    gemm_bt<<<dim3(29, 32), 256, 0, stream>>>(xqc, 3712, qW1T, 3712, qb1,
                                              Y1q, nullptr, 3712, 3712, 1);
    gemm_bt<<<dim3(16, 32), 256, 0, stream>>>(Y1q, 3712, qW2T, 3712, qb2,
                                              q_mu + (size_t)c * 4194304,
                                              q_sig + (size_t)c * 4194304, 3712, 0, 2);
  }

  samp_k<<<16384, 256, 0, stream>>>(noise_p, noise_q, out);
}